// Round 1
// baseline (400.251 us; speedup 1.0000x reference)
//
#include <hip/hip_runtime.h>

#define DIM 128
#define CHUNK 512

// Kernel 1: segment-sum of gathered char embeddings into t_buf [n_triples, 128].
// Exploits sorted segment_ids: each block owns a contiguous CHUNK of chars;
// thread d owns column d. Interior segment runs are plain stores; the first
// and last run of each chunk (may straddle chunk boundaries) use atomicAdd.
__global__ __launch_bounds__(128) void seg_sum_kernel(
    const float* __restrict__ char_emb,
    const int* __restrict__ char_ids,
    const int* __restrict__ seg_ids,
    float* __restrict__ t_buf,
    int total_chars)
{
    __shared__ int s_cid[CHUNK];
    __shared__ int s_sid[CHUNK];
    const int start = blockIdx.x * CHUNK;
    const int nn = min(CHUNK, total_chars - start);
    const int tid = threadIdx.x;  // 0..127 = column
    if (nn <= 0) return;

    for (int i = tid; i < nn; i += 128) {
        s_cid[i] = char_ids[start + i];
        s_sid[i] = seg_ids[start + i];
    }
    __syncthreads();

    float acc = 0.0f;
    int cur = s_sid[0];
    bool first = true;  // first flushed run may continue from previous chunk

    int c = 0;
    while (c < nn) {
        const int m = min(8, nn - c);
        float v[8];
#pragma unroll
        for (int j = 0; j < 8; ++j) {
            if (j < m) v[j] = char_emb[s_cid[c + j] * DIM + tid];  // 8 gathers in flight
        }
        for (int j = 0; j < m; ++j) {
            const int seg = s_sid[c + j];   // wave-uniform
            if (seg != cur) {
                if (first) {
                    atomicAdd(&t_buf[cur * DIM + tid], acc);
                    first = false;
                } else {
                    t_buf[cur * DIM + tid] = acc;  // interior run: sole writer
                }
                acc = 0.0f;
                cur = seg;
            }
            acc += v[j];
        }
        c += m;
    }
    // last run may continue into the next chunk -> atomic
    atomicAdd(&t_buf[cur * DIM + tid], acc);
}

// Kernel 2: three Frobenius reductions: ht = <H,T>, hh = <H,H>, tt = <T,T>.
// 32 lanes per row with float4 loads; 8 rows per 256-thread block iteration.
__global__ __launch_bounds__(256) void dot_kernel(
    const float* __restrict__ t_buf,
    const float* __restrict__ ent,
    const int* __restrict__ head_ids,
    double* __restrict__ sums,   // [0]=ht [1]=hh [2]=tt
    int n_triples)
{
    const int lane = threadIdx.x & 31;
    const int row_in_block = threadIdx.x >> 5;  // 0..7
    float ht = 0.f, hh = 0.f, tt = 0.f;

    for (int row = blockIdx.x * 8 + row_in_block; row < n_triples;
         row += gridDim.x * 8) {
        const float4 tv = ((const float4*)(t_buf + (size_t)row * DIM))[lane];
        const int h = head_ids[row];
        const float4 hv = ((const float4*)(ent + (size_t)h * DIM))[lane];
        ht += tv.x * hv.x + tv.y * hv.y + tv.z * hv.z + tv.w * hv.w;
        hh += hv.x * hv.x + hv.y * hv.y + hv.z * hv.z + hv.w * hv.w;
        tt += tv.x * tv.x + tv.y * tv.y + tv.z * tv.z + tv.w * tv.w;
    }

    // wave (64-lane) reduction
#pragma unroll
    for (int off = 32; off > 0; off >>= 1) {
        ht += __shfl_down(ht, off);
        hh += __shfl_down(hh, off);
        tt += __shfl_down(tt, off);
    }
    __shared__ float s_ht[4], s_hh[4], s_tt[4];
    const int wave = threadIdx.x >> 6;
    if ((threadIdx.x & 63) == 0) {
        s_ht[wave] = ht; s_hh[wave] = hh; s_tt[wave] = tt;
    }
    __syncthreads();
    if (threadIdx.x == 0) {
        float a = 0.f, b = 0.f, c = 0.f;
#pragma unroll
        for (int w = 0; w < 4; ++w) { a += s_ht[w]; b += s_hh[w]; c += s_tt[w]; }
        atomicAdd(&sums[0], (double)a);
        atomicAdd(&sums[1], (double)b);
        atomicAdd(&sums[2], (double)c);
    }
}

// Kernel 3: out = N - ht / (sqrt(hh) * sqrt(tt))
__global__ void finalize_kernel(const double* __restrict__ sums,
                                float* __restrict__ out, int n_triples)
{
    const double ht = sums[0], hh = sums[1], tt = sums[2];
    out[0] = (float)((double)n_triples - ht / sqrt(hh * tt));
}

extern "C" void kernel_launch(void* const* d_in, const int* in_sizes, int n_in,
                              void* d_out, int out_size, void* d_ws, size_t ws_size,
                              hipStream_t stream)
{
    const float* char_emb = (const float*)d_in[0];
    const float* ent_emb  = (const float*)d_in[1];
    const int* head_ids   = (const int*)d_in[2];
    const int* char_ids   = (const int*)d_in[3];
    const int* seg_ids    = (const int*)d_in[4];
    const int n_triples   = in_sizes[2];
    const int total_chars = in_sizes[3];

    float* t_buf = (float*)d_ws;
    const size_t t_bytes = (size_t)n_triples * DIM * sizeof(float);
    double* sums = (double*)((char*)d_ws + t_bytes);

    // zero T buffer + scalar accumulators (ws is re-poisoned before every call)
    hipMemsetAsync(d_ws, 0, t_bytes + 3 * sizeof(double), stream);

    const int n_chunks = (total_chars + CHUNK - 1) / CHUNK;
    seg_sum_kernel<<<n_chunks, 128, 0, stream>>>(char_emb, char_ids, seg_ids,
                                                 t_buf, total_chars);

    dot_kernel<<<1024, 256, 0, stream>>>(t_buf, ent_emb, head_ids, sums,
                                         n_triples);

    finalize_kernel<<<1, 1, 0, stream>>>(sums, (float*)d_out, n_triples);
}